// Round 2
// baseline (493.246 us; speedup 1.0000x reference)
//
#include <hip/hip_runtime.h>
#include <math.h>

// Problem constants (fixed by setup_inputs)
static constexpr int Cc   = 16;   // C
static constexpr int COc  = 16;   // CO
static constexpr int Hh   = 4;    // heads
static constexpr int CHc  = 4;    // CO/H
static constexpr int CPWc = 32;   // 2*C
static constexpr int NTH  = 256;  // block size

union F4 { float4 v; float f[4]; };

// Pin a wave-uniform float into an SGPR.
__device__ __forceinline__ float uni(float x) {
  return __uint_as_float(__builtin_amdgcn_readfirstlane(__float_as_uint(x)));
}

// ---------------------------------------------------------------------------
// Kernel 1: per-row first-layer projections (validated in round 1).
//   q rows: aW[r][j] = b1[j] + sum_i xq[i]*(w1[i][j]-w1[i+16][j])   (j<32)
//           aV[r][j] = bv1[j] + sum_i xq[i]*(v1[i][j]-v1[i+16][j])  (j<16)
//   k rows: cW[r][j] =          sum_i xk[i]*w1[i+16][j]
//           cV[r][j] =          sum_i xk[i]*v1[i+16][j]
// ---------------------------------------------------------------------------
__global__ __launch_bounds__(NTH) void ppa_precompute(
    const float* __restrict__ xq, const float* __restrict__ xk,
    const float* __restrict__ w1, const float* __restrict__ b1,
    const float* __restrict__ v1, const float* __restrict__ bv1,
    float* __restrict__ aW, float* __restrict__ aV,
    float* __restrict__ cW, float* __restrict__ cV,
    int BN, int BK) {
  __shared__ float sw1[CPWc * CPWc];  // 1024
  __shared__ float sv1[CPWc * COc];   // 512
  __shared__ float sb1[CPWc];
  __shared__ float sbv1[COc];
  const int t = threadIdx.x;
  for (int i = t; i < CPWc * CPWc; i += NTH) sw1[i] = w1[i];
  for (int i = t; i < CPWc * COc; i += NTH) sv1[i] = v1[i];
  if (t < CPWc) sb1[t] = b1[t];
  if (t < COc) sbv1[t] = bv1[t];
  __syncthreads();

  const int r = blockIdx.x * NTH + t;
  if (r >= BN + BK) return;
  const bool isQ = (r < BN);
  const int rr = isQ ? r : (r - BN);
  const float* src = isQ ? (xq + (size_t)rr * Cc) : (xk + (size_t)rr * Cc);

  float x[Cc];
#pragma unroll
  for (int i = 0; i < Cc; i += 4) {
    float4 v = *reinterpret_cast<const float4*>(src + i);
    x[i] = v.x; x[i + 1] = v.y; x[i + 2] = v.z; x[i + 3] = v.w;
  }

  if (isQ) {
#pragma unroll
    for (int j = 0; j < CPWc; ++j) {
      float acc = sb1[j];
#pragma unroll
      for (int i = 0; i < Cc; ++i)
        acc += x[i] * (sw1[i * CPWc + j] - sw1[(i + Cc) * CPWc + j]);
      aW[(size_t)rr * CPWc + j] = acc;
    }
#pragma unroll
    for (int j = 0; j < COc; ++j) {
      float acc = sbv1[j];
#pragma unroll
      for (int i = 0; i < Cc; ++i)
        acc += x[i] * (sv1[i * COc + j] - sv1[(i + Cc) * COc + j]);
      aV[(size_t)rr * COc + j] = acc;
    }
  } else {
#pragma unroll
    for (int j = 0; j < CPWc; ++j) {
      float acc = 0.f;
#pragma unroll
      for (int i = 0; i < Cc; ++i) acc += x[i] * sw1[(i + Cc) * CPWc + j];
      cW[(size_t)rr * CPWc + j] = acc;
    }
#pragma unroll
    for (int j = 0; j < COc; ++j) {
      float acc = 0.f;
#pragma unroll
      for (int i = 0; i < Cc; ++i) acc += x[i] * sv1[(i + Cc) * COc + j];
      cV[(size_t)rr * COc + j] = acc;
    }
  }
}

// ---------------------------------------------------------------------------
// Kernel 2: one block per (b,n) output row. 256 threads, each handles two
// k-values per iteration (2 iterations: Nk=1024). Logits are ReLU'd (>=0,
// O(1) magnitude) so softmax needs no max tracking: plain exp-sum.
// Row-uniform vectors (a, av, b2, bv2) live in SGPRs via readfirstlane.
// ---------------------------------------------------------------------------
__global__ __launch_bounds__(NTH, 3) void ppa_main(
    const float* __restrict__ aW, const float* __restrict__ aV,
    const float* __restrict__ cW, const float* __restrict__ cV,
    const float* __restrict__ w2, const float* __restrict__ b2,
    const float* __restrict__ v2, const float* __restrict__ bv2,
    float* __restrict__ out, int N, int Nk) {
  __shared__ float sw2[CPWc * Hh];   // [32][4] = 128
  __shared__ float sv2[COc * COc];   // [16][16] = 256
  __shared__ float sred[4][Hh + COc];

  const int t = threadIdx.x;
  const int row = blockIdx.x;  // [0, B*N)
  const int b = row / N;

  sv2[t] = v2[t];                    // NTH == 256 == COc*COc
  if (t < CPWc * Hh) sw2[t] = w2[t];
  __syncthreads();

  // Row-uniform values -> SGPRs.
  float a_[CPWc], av_[COc], b2_[Hh], bv2_[COc];
  {
    const float* ar = aW + (size_t)row * CPWc;
    const float* vr = aV + (size_t)row * COc;
#pragma unroll
    for (int j = 0; j < CPWc; ++j) a_[j] = uni(ar[j]);
#pragma unroll
    for (int j = 0; j < COc; ++j) av_[j] = uni(vr[j]);
#pragma unroll
    for (int h = 0; h < Hh; ++h) b2_[h] = uni(b2[h]);
#pragma unroll
    for (int c = 0; c < COc; ++c) bv2_[c] = uni(bv2[c]);
  }

  float l[Hh] = {0.f, 0.f, 0.f, 0.f};
  float o[COc];
#pragma unroll
  for (int c = 0; c < COc; ++c) o[c] = 0.f;

  const float* cWb = cW + (size_t)b * Nk * CPWc;
  const float* cVb = cV + (size_t)b * Nk * COc;

  for (int kk = 0; kk < Nk; kk += 2 * NTH) {
    const int k0 = kk + t;
    const int k1 = k0 + NTH;
    const float* pc0 = cWb + (size_t)k0 * CPWc;
    const float* pc1 = cWb + (size_t)k1 * CPWc;

    // ---- logits for both pairs: lg = relu(hw) @ w2 + b2, hw = relu(a + cW_k)
    float lg0[Hh], lg1[Hh];
#pragma unroll
    for (int h = 0; h < Hh; ++h) { lg0[h] = b2_[h]; lg1[h] = b2_[h]; }
#pragma unroll
    for (int j4 = 0; j4 < CPWc; j4 += 4) {
      F4 x0, x1;
      x0.v = *reinterpret_cast<const float4*>(pc0 + j4);
      x1.v = *reinterpret_cast<const float4*>(pc1 + j4);
#pragma unroll
      for (int jj = 0; jj < 4; ++jj) {
        const int j = j4 + jj;
        const float hw0 = fmaxf(a_[j] + x0.f[jj], 0.f);
        const float hw1 = fmaxf(a_[j] + x1.f[jj], 0.f);
        F4 w;
        w.v = *reinterpret_cast<const float4*>(&sw2[j * Hh]);
#pragma unroll
        for (int h = 0; h < Hh; ++h) {
          lg0[h] += hw0 * w.f[h];
          lg1[h] += hw1 * w.f[h];
        }
      }
    }
    float p0[Hh], p1[Hh];
#pragma unroll
    for (int h = 0; h < Hh; ++h) {
      p0[h] = __expf(fmaxf(lg0[h], 0.f));
      p1[h] = __expf(fmaxf(lg1[h], 0.f));
      l[h] += p0[h] + p1[h];
    }

    // ---- values for both pairs: val = relu(relu(av + cV_k) @ v2 + bv2)
    const float* pv0 = cVb + (size_t)k0 * COc;
    const float* pv1 = cVb + (size_t)k1 * COc;
    F4 cv0[4], cv1[4];
#pragma unroll
    for (int q = 0; q < 4; ++q) {
      cv0[q].v = *reinterpret_cast<const float4*>(pv0 + 4 * q);
      cv1[q].v = *reinterpret_cast<const float4*>(pv1 + 4 * q);
    }
    float v0[COc], v1[COc];
#pragma unroll
    for (int c = 0; c < COc; ++c) { v0[c] = bv2_[c]; v1[c] = bv2_[c]; }
#pragma unroll
    for (int j = 0; j < COc; ++j) {
      const float hv0 = fmaxf(av_[j] + cv0[j >> 2].f[j & 3], 0.f);
      const float hv1 = fmaxf(av_[j] + cv1[j >> 2].f[j & 3], 0.f);
#pragma unroll
      for (int c4 = 0; c4 < COc; c4 += 4) {
        F4 w;
        w.v = *reinterpret_cast<const float4*>(&sv2[j * COc + c4]);
#pragma unroll
        for (int cc = 0; cc < 4; ++cc) {
          v0[c4 + cc] += hv0 * w.f[cc];
          v1[c4 + cc] += hv1 * w.f[cc];
        }
      }
    }
#pragma unroll
    for (int c = 0; c < COc; ++c) {
      o[c] += p0[c >> 2] * fmaxf(v0[c], 0.f) + p1[c >> 2] * fmaxf(v1[c], 0.f);
    }
  }

  // ---- plain-sum reduction: wave butterfly, then cross-wave via LDS.
#pragma unroll
  for (int off = 1; off < 64; off <<= 1) {
#pragma unroll
    for (int h = 0; h < Hh; ++h) l[h] += __shfl_xor(l[h], off);
#pragma unroll
    for (int c = 0; c < COc; ++c) o[c] += __shfl_xor(o[c], off);
  }
  const int lane = t & 63;
  const int wid = t >> 6;
  if (lane == 0) {
#pragma unroll
    for (int h = 0; h < Hh; ++h) sred[wid][h] = l[h];
#pragma unroll
    for (int c = 0; c < COc; ++c) sred[wid][Hh + c] = o[c];
  }
  __syncthreads();

  if (t < COc) {
    const int h = t >> 2;
    float lsum = 0.f, osum = 0.f;
#pragma unroll
    for (int w = 0; w < 4; ++w) {
      lsum += sred[w][h];
      osum += sred[w][Hh + t];
    }
    out[(size_t)row * COc + t] = osum / lsum;
  }
}

// ---------------------------------------------------------------------------
extern "C" void kernel_launch(void* const* d_in, const int* in_sizes, int n_in,
                              void* d_out, int out_size, void* d_ws, size_t ws_size,
                              hipStream_t stream) {
  const float* xq  = (const float*)d_in[0];
  const float* xk  = (const float*)d_in[1];
  const float* w1  = (const float*)d_in[2];
  const float* b1  = (const float*)d_in[3];
  const float* w2  = (const float*)d_in[4];
  const float* b2  = (const float*)d_in[5];
  const float* v1  = (const float*)d_in[6];
  const float* bv1 = (const float*)d_in[7];
  const float* v2  = (const float*)d_in[8];
  const float* bv2 = (const float*)d_in[9];
  float* out = (float*)d_out;

  const int BN = in_sizes[0] / Cc;  // B*N  = 2048
  const int BK = in_sizes[1] / Cc;  // B*Nk = 2048
  const int B = 2;                  // fixed by setup_inputs
  const int N = BN / B;
  const int Nk = BK / B;

  float* ws = (float*)d_ws;
  float* aW = ws;                          // BN*32
  float* aV = aW + (size_t)BN * CPWc;      // BN*16
  float* cW = aV + (size_t)BN * COc;       // BK*32
  float* cV = cW + (size_t)BK * CPWc;      // BK*16

  const int totalRows = BN + BK;
  const int pgrid = (totalRows + NTH - 1) / NTH;
  ppa_precompute<<<pgrid, NTH, 0, stream>>>(xq, xk, w1, b1, v1, bv1,
                                            aW, aV, cW, cV, BN, BK);
  ppa_main<<<BN, NTH, 0, stream>>>(aW, aV, cW, cV, w2, b2, v2, bv2, out, N, Nk);
}